// Round 8
// baseline (1769.700 us; speedup 1.0000x reference)
//
#include <hip/hip_runtime.h>

// ---------------------------------------------------------------------------
// RatingLayer: 2-round fully-connected 2-node GRU + linear head.
// One [24576,4096]^T bf16 GEMM per round. Round 8: B operand loaded DIRECTLY
// to registers from a fragment-linear W layout (Wf) built once in prep —
// removes all B ds_reads + B staging (LDS-BW was the r7 bottleneck:
// 192 ds_read_b128/tile/CU ~2300cy vs 2483cy MFMA window). A path unchanged
// (gload16+XOR swizzle). LDS 64KB (A only).
// ---------------------------------------------------------------------------

typedef __bf16 bf16x8 __attribute__((ext_vector_type(8)));
typedef float  f32x4  __attribute__((ext_vector_type(4)));
typedef unsigned short u16x4 __attribute__((ext_vector_type(4)));
typedef unsigned short u16x8 __attribute__((ext_vector_type(8)));

#define HH    4096
#define NI_D  2048
#define N3H   12288
#define N6H   24576
#define BSZ   4096
#define BM    256
#define BN    256
#define BK    64
#define MT    (BSZ / BM)     // 16
#define NT    (N6H / BN)     // 96
#define GRID_GEMM (MT * NT)  // 1536
#define NKT   (HH / BK)      // 64 K-tiles

// Wf fragment-linear layout: frag-row g16 = W-row/16 (1536 of them), k-chunk
// kc = k/8 (512), lane slot = W-row%16.  byte = g16*131072 + kc*256 + slot*16.
// A wave's 16x16x32 B-fragment (16 rows x 8 k-elems per lane) is then ONE
// contiguous 1KB block: addr = g16*131072 + kbase*32 + lane*16.
#define NB_W  49152          // (24576/16) * (4096/128) transform blocks
#define NB_C  16384

__device__ __forceinline__ unsigned short f2bf(float f) {
  unsigned u = __float_as_uint(f);
  u += 0x7FFFu + ((u >> 16) & 1u);
  return (unsigned short)(u >> 16);
}
__device__ __forceinline__ float bf2f(unsigned short s) {
  return __uint_as_float(((unsigned)s) << 16);
}

__device__ __forceinline__ void gload16(const void* g, void* l) {
  void* gv = (void*)g;
  __builtin_amdgcn_global_load_lds(
      (__attribute__((address_space(1))) unsigned int*)gv,
      (__attribute__((address_space(3))) unsigned int*)l,
      16, 0, 0);
}

// --- fused prep: Wf (frag-linear, col-half-swapped+stacked W) ; hb = bf16(feat)
__global__ void __launch_bounds__(256)
prep(const float* __restrict__ Wih, const float* __restrict__ Whh,
     const float* __restrict__ feat,
     unsigned short* __restrict__ Wf, unsigned short* __restrict__ hb)
{
  int bid = blockIdx.x;
  int t = threadIdx.x;
  if (bid < NB_W) {
    // block covers 16 W-rows (jg) x 128 k (kcg): reads 128B/row coalesced,
    // writes 1KB/wave contiguous in Wf.
    int jg  = bid >> 5;          // 0..1535
    int kcg = bid & 31;          // 0..31
    int j   = jg * 16 + (t & 15);
    int kc  = kcg * 16 + (t >> 4);
    int k   = kc * 8;
    const float* src;
    if (j < N3H) src = Wih + (size_t)j * HH + ((k + NI_D) & (HH - 1));
    else         src = Whh + (size_t)(j - N3H) * HH + k;
    f32x4 v0 = *(const f32x4*)src;
    f32x4 v1 = *(const f32x4*)(src + 4);
    u16x8 o = { f2bf(v0[0]), f2bf(v0[1]), f2bf(v0[2]), f2bf(v0[3]),
                f2bf(v1[0]), f2bf(v1[1]), f2bf(v1[2]), f2bf(v1[3]) };
    *(u16x8*)(Wf + (size_t)jg * 65536 + kc * 128 + (t & 15) * 8) = o;
  } else {
    int i = ((bid - NB_W) * 256 + t) << 2;
    f32x4 v = *(const f32x4*)(feat + i);
    u16x4 o = { f2bf(v[0]), f2bf(v[1]), f2bf(v[2]), f2bf(v[3]) };
    *(u16x4*)(hb + i) = o;
  }
}

// ---------------------------------------------------------------------------
// GEMM helpers. LDS (A only): buf d at d*32768 (256 rows x 128 B).
// Granule g = 64 rows = one gload16 per thread (8 KB). Linear LDS dest; global
// source column pre-swizzled by ((row&7)<<4) (rule 21 both-sides).
// A frags 4-7 live in granules G1(wm0)/G3(wm1); frags 0-3 in G0/G2.
// ---------------------------------------------------------------------------
__device__ __forceinline__ void stageA(const char* a_base, char* lds, int ldst,
                                       int d, int kt, int g) {
  int kc = (kt < NKT) ? kt : 0;                 // dummy tail loads, race-safe
  gload16(a_base + (size_t)kc * 128 + (size_t)g * 524288,
          lds + d * 32768 + g * 8192 + ldst);
}

template <int MB, int NB>
__device__ __forceinline__ void mfmaQ(f32x4 (&acc)[8][4],
                                      const bf16x8 (&af)[4][2],
                                      const bf16x8 (&bf)[2][2]) {
  __builtin_amdgcn_s_setprio(1);
#pragma unroll
  for (int ks = 0; ks < 2; ++ks)
#pragma unroll
    for (int mf = 0; mf < 4; ++mf)
#pragma unroll
      for (int nf = 0; nf < 2; ++nf)
        acc[MB + mf][NB + nf] = __builtin_amdgcn_mfma_f32_16x16x32_bf16(
            af[mf][ks], bf[nf][ks], acc[MB + mf][NB + nf], 0, 0, 0);
  __builtin_amdgcn_s_setprio(0);
}

#define BAR   __builtin_amdgcn_s_barrier()
#define SB    __builtin_amdgcn_sched_barrier(0)
#define LGKM0 do { asm volatile("s_waitcnt lgkmcnt(0)" ::: "memory"); SB; } while (0)
#define VM12  asm volatile("s_waitcnt vmcnt(12)" ::: "memory")

// One K-tile. Per-wave vmem issue ledger (steady state, tile t):
//   ph0: b23(t) x4 global + stage A(t+1)G0,G2 -> D^1  (6)
//   ph1: stage A(t+2)G1,G3 -> D                       (2)
//   ph3: b01(t+1) x4 global                           (4)
// Gates: ph0-end vmcnt(12) -> A(t)G0,G2 (staged t-1 ph0) landed, for ph1's
//   a03 ds_reads   [pool: t-1ph1 2 + t-1ph3 4 + t ph0 6 = 12]
//        ph2-end vmcnt(12) -> A(t+1)G1,G3 (staged t-1 ph1) landed, for ph3's
//   a47 ds_reads   [pool: t-1ph3 4 + t ph0 6 + t ph1 2 = 12]
// B-register readiness is compiler-tracked (plain loads). Never vmcnt(0).
// LDS overwrite: D^1 G0,G2 (=a03(t-1)) read t-1 ph1, barriered; D G1,G3
//   (=a47(t)) read t-1 ph3, barriered by t ph0. Safe.
template <int D>
__device__ __forceinline__ void kblock(char* lds, const char* a_base,
                                       const char* wfk, int ldst,
                                       int aro, int offk0, int offk1,
                                       int tcur, f32x4 (&acc)[8][4],
                                       bf16x8 (&a47)[4][2], bf16x8 (&a03)[4][2],
                                       bf16x8 (&b01)[2][2], bf16x8 (&b23)[2][2]) {
  const char* LA  = lds + D * 32768 + aro;
  const char* LAn = lds + (D ^ 1) * 32768 + aro;

  // ---- ph0: MFMA(a47,b01). Issue b23(t) globals; stage A(t+1)G0,G2 -> D^1.
#pragma unroll
  for (int nf = 0; nf < 2; ++nf)
#pragma unroll
    for (int kh = 0; kh < 2; ++kh)
      b23[nf][kh] = *(const bf16x8*)(wfk + (2 + nf) * 131072 + kh * 1024);
  stageA(a_base, lds, ldst, D ^ 1, tcur + 1, 0);
  stageA(a_base, lds, ldst, D ^ 1, tcur + 1, 2);
  LGKM0;                                 // a47 ds_reads (prev ph3) landed
  mfmaQ<4, 0>(acc, a47, b01);
  VM12;                                  // A(t)G0,G2 LDS valid for ph1 reads
  BAR;

  // ---- ph1: MFMA(a47,b23). Read-ahead a03(t); stage A(t+2)G1,G3 -> D.
#pragma unroll
  for (int mf = 0; mf < 4; ++mf) {
    a03[mf][0] = *(const bf16x8*)(LA + mf * 2048 + offk0);
    a03[mf][1] = *(const bf16x8*)(LA + mf * 2048 + offk1);
  }
  stageA(a_base, lds, ldst, D, tcur + 2, 1);
  stageA(a_base, lds, ldst, D, tcur + 2, 3);
  SB;
  mfmaQ<4, 2>(acc, a47, b23);            // compiler auto-waits b23 vmcnt
  BAR;

  // ---- ph2: MFMA(a03,b01).
  LGKM0;                                 // a03 landed
  mfmaQ<0, 0>(acc, a03, b01);
  VM12;                                  // A(t+1)G1,G3 LDS valid for ph3 reads
  BAR;

  // ---- ph3: MFMA(a03,b23). Read-ahead a47(t+1) from D^1; issue b01(t+1).
#pragma unroll
  for (int mf = 0; mf < 4; ++mf) {
    a47[mf][0] = *(const bf16x8*)(LAn + (4 + mf) * 2048 + offk0);
    a47[mf][1] = *(const bf16x8*)(LAn + (4 + mf) * 2048 + offk1);
  }
#pragma unroll
  for (int nf = 0; nf < 2; ++nf)
#pragma unroll
    for (int kh = 0; kh < 2; ++kh)
      b01[nf][kh] = *(const bf16x8*)(wfk + 2048 + nf * 131072 + kh * 1024);
  SB;
  mfmaQ<0, 2>(acc, a03, b23);
  BAR;
}

// ---------------------------------------------------------------------------
// C[4096, 24576] bf16 = A[4096,4096] * Wf^T (frag-layout)  (bf16 in/out)
// 256x256 tile, BK=64, 512 threads (8 waves, 2Mx4N), LDS 64 KB (A dbuf).
// ---------------------------------------------------------------------------
__global__ void __launch_bounds__(512, 2)
gemm_bt(const unsigned short* __restrict__ A,
        const unsigned short* __restrict__ Wf,
        unsigned short* __restrict__ C)
{
  __shared__ alignas(16) char lds[65536];

  int bid = blockIdx.x;
  int wg  = (bid & 7) * (GRID_GEMM / 8) + (bid >> 3);  // XCD swizzle, 1536%8==0
  int nt  = wg / MT;          // n-major: 16 consecutive wg share one W panel
  int mt  = wg % MT;
  int m0  = mt * BM;
  int n0  = nt * BN;

  int t  = threadIdx.x;
  int wv = t >> 6;
  int l  = t & 63;
  int wm = wv >> 2;
  int wn = wv & 3;

  // A staging: thread covers row rloc of a 64-row granule, 16B chunk (l&7),
  // source column XOR-preswizzled by row&7 = l>>3.
  int rloc   = wv * 8 + (l >> 3);
  int sg_col = ((l & 7) ^ (l >> 3)) << 4;
  const char* a_base = (const char*)A + (size_t)(m0 + rloc) * 8192 + sg_col;
  int ldst = wv * 1024;

  // A read-side swizzled offsets
  int offk0 = ((l >> 4) << 4) ^ ((l & 7) << 4);
  int offk1 = offk0 ^ 64;
  int aro = (wm * 128 + (l & 15)) * 128;

  // B fragment base: frag nf at +nf*131072, k-half at +kh*1024, tile at +kt*2048
  const char* wfb = (const char*)Wf +
                    ((size_t)(n0 >> 4) + wn * 4) * 131072 + (size_t)l * 16;

  f32x4 acc[8][4] = {};
  bf16x8 a47[4][2], a03[4][2], b01[2][2], b23[2][2];

  // prologue: A(0) all granules -> D0; A(1) G1,G3 -> D1; b01(0) globals.
#pragma unroll
  for (int g = 0; g < 4; ++g) stageA(a_base, lds, ldst, 0, 0, g);
  stageA(a_base, lds, ldst, 1, 1, 1);
  stageA(a_base, lds, ldst, 1, 1, 3);
#pragma unroll
  for (int nf = 0; nf < 2; ++nf)
#pragma unroll
    for (int kh = 0; kh < 2; ++kh)
      b01[nf][kh] = *(const bf16x8*)(wfb + nf * 131072 + kh * 1024);
  asm volatile("s_waitcnt vmcnt(6)" ::: "memory");   // A(0) landed
  BAR;
  {
    const char* LA0 = lds + aro;
#pragma unroll
    for (int mf = 0; mf < 4; ++mf) {
      a47[mf][0] = *(const bf16x8*)(LA0 + (4 + mf) * 2048 + offk0);
      a47[mf][1] = *(const bf16x8*)(LA0 + (4 + mf) * 2048 + offk1);
    }
  }

#pragma unroll 1
  for (int tt = 0; tt < NKT; tt += 2) {
    const char* wfk = wfb + (size_t)tt * 2048;
    kblock<0>(lds, a_base, wfk, ldst, aro, offk0, offk1,
              tt, acc, a47, a03, b01, b23);
    kblock<1>(lds, a_base, wfk + 2048, ldst, aro, offk0, offk1,
              tt + 1, acc, a47, a03, b01, b23);
  }
  asm volatile("s_waitcnt vmcnt(0) lgkmcnt(0)" ::: "memory");  // drain tails

  // C-write: frag layout col = lane&15, row = (lane>>4)*4 + reg (m89)
  int crow = m0 + wm * 128 + ((l >> 4) << 2);
  int ccol = n0 + wn * 64 + (l & 15);
#pragma unroll
  for (int mf = 0; mf < 8; ++mf)
#pragma unroll
    for (int nf = 0; nf < 4; ++nf)
#pragma unroll
      for (int i = 0; i < 4; ++i)
        C[(size_t)(crow + mf * 16 + i) * N6H + (ccol + nf * 16)] =
            f2bf(acc[mf][nf][i]);
}

// --- round-1 GRU: h_old = features (f32); writes h1 as bf16 only (linear).
__global__ void __launch_bounds__(256)
gru1(const unsigned short* __restrict__ C, const float* __restrict__ h_old,
     const float* __restrict__ b_ih, const float* __restrict__ b_hh,
     unsigned short* __restrict__ h_bf)
{
  int idx = blockIdx.x * 256 + threadIdx.x;
  int b = idx >> 10;
  int j = (idx & 1023) << 2;
  const unsigned short* Cr = C + (size_t)b * N6H;
  u16x4 gir = *(const u16x4*)(Cr + j);
  u16x4 giz = *(const u16x4*)(Cr + HH + j);
  u16x4 gin = *(const u16x4*)(Cr + 2 * HH + j);
  u16x4 ghr = *(const u16x4*)(Cr + 3 * HH + j);
  u16x4 ghz = *(const u16x4*)(Cr + 4 * HH + j);
  u16x4 ghn = *(const u16x4*)(Cr + 5 * HH + j);
  f32x4 bir = *(const f32x4*)(b_ih + j);
  f32x4 biz = *(const f32x4*)(b_ih + HH + j);
  f32x4 bin = *(const f32x4*)(b_ih + 2 * HH + j);
  f32x4 bhr = *(const f32x4*)(b_hh + j);
  f32x4 bhz = *(const f32x4*)(b_hh + HH + j);
  f32x4 bhn = *(const f32x4*)(b_hh + 2 * HH + j);
  f32x4 ho  = *(const f32x4*)(h_old + (size_t)b * HH + j);
  u16x4 hb;
#pragma unroll
  for (int e = 0; e < 4; ++e) {
    float r = 1.f / (1.f + expf(-(bf2f(gir[e]) + bir[e] + bf2f(ghr[e]) + bhr[e])));
    float z = 1.f / (1.f + expf(-(bf2f(giz[e]) + biz[e] + bf2f(ghz[e]) + bhz[e])));
    float n = tanhf(bf2f(gin[e]) + bin[e] + r * (bf2f(ghn[e]) + bhn[e]));
    hb[e] = f2bf((1.f - z) * n + z * ho[e]);
  }
  *(u16x4*)(h_bf + (size_t)b * HH + j) = hb;
}

// --- round-2 GRU fused with FC head.
__global__ void __launch_bounds__(256)
gru2_fc(const unsigned short* __restrict__ C,
        const unsigned short* __restrict__ h_old_bf,
        const float* __restrict__ b_ih, const float* __restrict__ b_hh,
        const float* __restrict__ fcw, const float* __restrict__ fcb,
        float* __restrict__ out)
{
  int idx = blockIdx.x * 256 + threadIdx.x;
  int b = idx >> 10;
  int j = (idx & 1023) << 2;
  const unsigned short* Cr = C + (size_t)b * N6H;
  u16x4 gir = *(const u16x4*)(Cr + j);
  u16x4 giz = *(const u16x4*)(Cr + HH + j);
  u16x4 gin = *(const u16x4*)(Cr + 2 * HH + j);
  u16x4 ghr = *(const u16x4*)(Cr + 3 * HH + j);
  u16x4 ghz = *(const u16x4*)(Cr + 4 * HH + j);
  u16x4 ghn = *(const u16x4*)(Cr + 5 * HH + j);
  f32x4 bir = *(const f32x4*)(b_ih + j);
  f32x4 biz = *(const f32x4*)(b_ih + HH + j);
  f32x4 bin = *(const f32x4*)(b_ih + 2 * HH + j);
  f32x4 bhr = *(const f32x4*)(b_hh + j);
  f32x4 bhz = *(const f32x4*)(b_hh + HH + j);
  f32x4 bhn = *(const f32x4*)(b_hh + 2 * HH + j);
  u16x4 hob = *(const u16x4*)(h_old_bf + (size_t)b * HH + j);
  f32x4 fw  = *(const f32x4*)(fcw + j);
  float s = 0.f;
#pragma unroll
  for (int e = 0; e < 4; ++e) {
    float r = 1.f / (1.f + expf(-(bf2f(gir[e]) + bir[e] + bf2f(ghr[e]) + bhr[e])));
    float z = 1.f / (1.f + expf(-(bf2f(giz[e]) + biz[e] + bf2f(ghz[e]) + bhz[e])));
    float n = tanhf(bf2f(gin[e]) + bin[e] + r * (bf2f(ghn[e]) + bhn[e]));
    float h = (1.f - z) * n + z * bf2f(hob[e]);
    s += h * fw[e];
  }
#pragma unroll
  for (int off = 32; off > 0; off >>= 1) s += __shfl_down(s, off);
  __shared__ float red[4];
  if ((threadIdx.x & 63) == 0) red[threadIdx.x >> 6] = s;
  __syncthreads();
  if (threadIdx.x == 0) {
    float v = red[0] + red[1] + red[2] + red[3];
    if ((blockIdx.x & 3) == 0) v += fcb[0];
    atomicAdd(&out[b], v);
  }
}

extern "C" void kernel_launch(void* const* d_in, const int* in_sizes, int n_in,
                              void* d_out, int out_size, void* d_ws, size_t ws_size,
                              hipStream_t stream)
{
  const float* feat = (const float*)d_in[0];
  const float* Wih  = (const float*)d_in[1];
  const float* bih  = (const float*)d_in[2];
  const float* Whh  = (const float*)d_in[3];
  const float* bhh  = (const float*)d_in[4];
  const float* fcw  = (const float*)d_in[5];
  const float* fcb  = (const float*)d_in[6];
  float* out = (float*)d_out;

  char* ws = (char*)d_ws;
  unsigned short* Wf   = (unsigned short*)ws;                    // 201326592 B
  unsigned short* Cbuf = (unsigned short*)(ws + 201326592);      // 201326592 B
  unsigned short* hb   = (unsigned short*)(ws + 402653184);      //  33554432 B
  // total: 436207616 B

  hipMemsetAsync(out, 0, (size_t)out_size * sizeof(float), stream);
  prep<<<NB_W + NB_C, 256, 0, stream>>>(Wih, Whh, feat, Wf, hb);

  gemm_bt<<<GRID_GEMM, 512, 0, stream>>>(hb, Wf, Cbuf);
  gru1<<<16384, 256, 0, stream>>>(Cbuf, feat, bih, bhh, hb);

  gemm_bt<<<GRID_GEMM, 512, 0, stream>>>(hb, Wf, Cbuf);
  gru2_fc<<<16384, 256, 0, stream>>>(Cbuf, hb, bih, bhh, fcw, fcb, out);
}

// Round 9
// 1613.772 us; speedup vs baseline: 1.0966x; 1.0966x over previous
//
#include <hip/hip_runtime.h>

// ---------------------------------------------------------------------------
// RatingLayer: 2-round fully-connected 2-node GRU + linear head.
// One [24576,4096]^T bf16 GEMM per round. Round 9 = round 7 (best: read-ahead
// quadrant phases, counted vmcnt, B in LDS) + (a) NT cache policy on A staging
// (A is the 6x-restreamed operand; protect W panels in per-XCD L2),
// (b) lgkmcnt(8) throttle in the 12-read phase (m201 template element).
// r8's B-in-registers REVERTED: compiler-tracked B loads shared the vmcnt
// counter with the hand-counted ladder and drained it (42% MfmaUtil).
// ---------------------------------------------------------------------------

typedef __bf16 bf16x8 __attribute__((ext_vector_type(8)));
typedef float  f32x4  __attribute__((ext_vector_type(4)));
typedef unsigned short u16x4 __attribute__((ext_vector_type(4)));

#define HH    4096
#define NI_D  2048
#define N3H   12288
#define N6H   24576
#define BSZ   4096
#define BM    256
#define BN    256
#define BK    64
#define MT    (BSZ / BM)     // 16
#define NT    (N6H / BN)     // 96
#define GRID_GEMM (MT * NT)  // 1536
#define NKT   (HH / BK)      // 64 K-tiles

#define NB_W  98304
#define NB_C  16384

__device__ __forceinline__ unsigned short f2bf(float f) {
  unsigned u = __float_as_uint(f);
  u += 0x7FFFu + ((u >> 16) & 1u);
  return (unsigned short)(u >> 16);
}
__device__ __forceinline__ float bf2f(unsigned short s) {
  return __uint_as_float(((unsigned)s) << 16);
}

__device__ __forceinline__ void gload16(const void* g, void* l) {
  void* gv = (void*)g;
  __builtin_amdgcn_global_load_lds(
      (__attribute__((address_space(1))) unsigned int*)gv,
      (__attribute__((address_space(3))) unsigned int*)l,
      16, 0, 0);
}
// NT variant (CPol bit1 = NT on gfx94x+): evict-first in L2. Used for A only.
__device__ __forceinline__ void gload16_nt(const void* g, void* l) {
  void* gv = (void*)g;
  __builtin_amdgcn_global_load_lds(
      (__attribute__((address_space(1))) unsigned int*)gv,
      (__attribute__((address_space(3))) unsigned int*)l,
      16, 0, 2);
}

// --- fused prep: Wc[j][k] = bf16(j<3H ? W_ih[j][(k+NI)%H] : W_hh[j-3H][k]);
//     hb = bf16(features)
__global__ void __launch_bounds__(256)
prep(const float* __restrict__ Wih, const float* __restrict__ Whh,
     const float* __restrict__ feat,
     unsigned short* __restrict__ Wc, unsigned short* __restrict__ hb)
{
  int bid = blockIdx.x;
  if (bid < NB_W) {
    int idx = (bid * 256 + threadIdx.x) << 2;
    int j = idx >> 12;
    int k = idx & 4095;
    const float* src;
    if (j < N3H) src = Wih + (size_t)j * HH + ((k + NI_D) & (HH - 1));
    else         src = Whh + (size_t)(j - N3H) * HH + k;
    f32x4 v = *(const f32x4*)src;
    u16x4 o = { f2bf(v[0]), f2bf(v[1]), f2bf(v[2]), f2bf(v[3]) };
    *(u16x4*)(Wc + idx) = o;
  } else {
    int i = ((bid - NB_W) * 256 + threadIdx.x) << 2;
    f32x4 v = *(const f32x4*)(feat + i);
    u16x4 o = { f2bf(v[0]), f2bf(v[1]), f2bf(v[2]), f2bf(v[3]) };
    *(u16x4*)(hb + i) = o;
  }
}

// ---------------------------------------------------------------------------
// GEMM helpers. LDS: buf d: A at d*32768 (256 rows x 128 B), B at 65536+d*32768.
// Granule g = 64 rows = one gload16 per thread (8 KB). Linear LDS dest; global
// source column pre-swizzled by ((row&7)<<4) (rule 21 both-sides).
// A frags 4-7 live in granules G1(wm0)/G3(wm1); frags 0-3 in G0/G2.
// ---------------------------------------------------------------------------
__device__ __forceinline__ void stageA(const char* a_base, char* lds, int ldst,
                                       int d, int kt, int g) {
  int kc = (kt < NKT) ? kt : 0;                 // dummy tail loads, race-safe
  gload16_nt(a_base + (size_t)kc * 128 + (size_t)g * 524288,
             lds + d * 32768 + g * 8192 + ldst);
}
__device__ __forceinline__ void stageB(const char* b_base, char* lds, int ldst,
                                       int d, int kt, int g) {
  int kc = (kt < NKT) ? kt : 0;
  gload16(b_base + (size_t)kc * 128 + (size_t)g * 524288,
          lds + 65536 + d * 32768 + g * 8192 + ldst);
}

// One C-quadrant over full K=64: 16 MFMAs into acc[MB..MB+3][NB..NB+1].
template <int MB, int NB>
__device__ __forceinline__ void mfmaQ(f32x4 (&acc)[8][4],
                                      const bf16x8 (&af)[4][2],
                                      const bf16x8 (&bf)[2][2]) {
  __builtin_amdgcn_s_setprio(1);
#pragma unroll
  for (int ks = 0; ks < 2; ++ks)
#pragma unroll
    for (int mf = 0; mf < 4; ++mf)
#pragma unroll
      for (int nf = 0; nf < 2; ++nf)
        acc[MB + mf][NB + nf] = __builtin_amdgcn_mfma_f32_16x16x32_bf16(
            af[mf][ks], bf[nf][ks], acc[MB + mf][NB + nf], 0, 0, 0);
  __builtin_amdgcn_s_setprio(0);
}

#define BAR   __builtin_amdgcn_s_barrier()
#define SB    __builtin_amdgcn_sched_barrier(0)
#define LGKM0 do { asm volatile("s_waitcnt lgkmcnt(0)" ::: "memory"); SB; } while (0)
#define LGKM8 asm volatile("s_waitcnt lgkmcnt(8)" ::: "memory")
#define VM6   asm volatile("s_waitcnt vmcnt(6)" ::: "memory")

// One K-tile, read-ahead schedule (r7, race-verified). On entry: a47c/b01c
// hold this tile's fragments (read during previous tile's ph3, landed via
// ph0's LGKM0). ph3 fills a47n/b01n from buffer D^1 for the next tile.
// Stage ledger per wave (steady state):
//   ph0: A(t1)G0,G2 -> D^1 | ph1: A(t2)G1,G3 -> D | ph2: B(t2)G0,G1 -> D
//   ph3: B(t2)G2,G3 -> D
// Gates: ph0 vmcnt(6) retires (t-1)ph1-and-older -> a03(t) staging landed.
//        ph2 vmcnt(6) retires (t-1)ph3-and-older -> D^1 fully valid for ph3
//        reads. Every staged LDS region's readers completed a barrier earlier.
template <int D>
__device__ __forceinline__ void kblock(char* lds, const char* a_base,
                                       const char* b_base, int ldst,
                                       int aro, int bro, int offk0, int offk1,
                                       int t1, int t2, f32x4 (&acc)[8][4],
                                       bf16x8 (&a47c)[4][2], bf16x8 (&b01c)[2][2],
                                       bf16x8 (&a47n)[4][2], bf16x8 (&b01n)[2][2]) {
  const char* LA  = lds + D * 32768 + aro;
  const char* LB  = lds + 65536 + D * 32768 + bro;
  const char* LAn = lds + (D ^ 1) * 32768 + aro;
  const char* LBn = lds + 65536 + (D ^ 1) * 32768 + bro;
  bf16x8 a03[4][2], b23[2][2];

  // ---- ph0: MFMA(a47,b01); read-ahead b23; stage A(t1)G0,G2 -> D^1.
  LGKM0;                                 // a47c,b01c landed
#pragma unroll
  for (int nf = 0; nf < 2; ++nf) {
    b23[nf][0] = *(const bf16x8*)(LB + (2 + nf) * 2048 + offk0);
    b23[nf][1] = *(const bf16x8*)(LB + (2 + nf) * 2048 + offk1);
  }
  stageA(a_base, lds, ldst, D ^ 1, t1, 0);
  stageA(a_base, lds, ldst, D ^ 1, t1, 2);
  SB;
  mfmaQ<4, 0>(acc, a47c, b01c);
  VM6;
  BAR;

  // ---- ph1: MFMA(a47,b23); read-ahead a03; stage A(t2)G1,G3 -> D.
  LGKM0;                                 // b23 landed (flew under ph0 MFMA)
#pragma unroll
  for (int mf = 0; mf < 4; ++mf) {
    a03[mf][0] = *(const bf16x8*)(LA + mf * 2048 + offk0);
    a03[mf][1] = *(const bf16x8*)(LA + mf * 2048 + offk1);
  }
  stageA(a_base, lds, ldst, D, t2, 1);
  stageA(a_base, lds, ldst, D, t2, 3);
  SB;
  mfmaQ<4, 2>(acc, a47c, b23);
  BAR;

  // ---- ph2: MFMA(a03,b01); stage B(t2)G0,G1 -> D; gate D^1 validity.
  LGKM0;                                 // a03 landed
  stageB(b_base, lds, ldst, D, t2, 0);
  stageB(b_base, lds, ldst, D, t2, 1);
  SB;
  mfmaQ<0, 0>(acc, a03, b01c);
  VM6;
  BAR;

  // ---- ph3: MFMA(a03,b23); read-ahead next tile's a47,b01 from D^1;
  //           stage B(t2)G2,G3 -> D; lgkm(8) throttle (12 reads this phase).
#pragma unroll
  for (int mf = 0; mf < 4; ++mf) {
    a47n[mf][0] = *(const bf16x8*)(LAn + (4 + mf) * 2048 + offk0);
    a47n[mf][1] = *(const bf16x8*)(LAn + (4 + mf) * 2048 + offk1);
  }
#pragma unroll
  for (int nf = 0; nf < 2; ++nf) {
    b01n[nf][0] = *(const bf16x8*)(LBn + nf * 2048 + offk0);
    b01n[nf][1] = *(const bf16x8*)(LBn + nf * 2048 + offk1);
  }
  stageB(b_base, lds, ldst, D, t2, 2);
  stageB(b_base, lds, ldst, D, t2, 3);
  LGKM8;                                 // drain 4 of 12 before barrier
  SB;
  mfmaQ<0, 2>(acc, a03, b23);
  BAR;
}

// ---------------------------------------------------------------------------
// C[4096, 24576] bf16 = A[4096,4096] * B[24576,4096]^T   (bf16 in, bf16 out)
// 256x256 tile, BK=64, 512 threads (8 waves, 2Mx4N), LDS 128 KB (2 dbuf).
// ---------------------------------------------------------------------------
__global__ void __launch_bounds__(512, 2)
gemm_bt(const unsigned short* __restrict__ A,
        const unsigned short* __restrict__ B,
        unsigned short* __restrict__ C)
{
  __shared__ alignas(16) char lds[131072];

  int bid = blockIdx.x;
  int wg  = (bid & 7) * (GRID_GEMM / 8) + (bid >> 3);  // XCD swizzle, 1536%8==0
  int nt  = wg / MT;          // n-major: 16 consecutive wg share one W panel
  int mt  = wg % MT;
  int m0  = mt * BM;
  int n0  = nt * BN;

  int t  = threadIdx.x;
  int wv = t >> 6;
  int l  = t & 63;
  int wm = wv >> 2;
  int wn = wv & 3;

  // staging: thread covers row rloc of a 64-row granule, 16B chunk (l&7),
  // source column XOR-preswizzled by row&7 = l>>3.
  int rloc   = wv * 8 + (l >> 3);
  int sg_col = ((l & 7) ^ (l >> 3)) << 4;
  const char* a_base = (const char*)A + (size_t)(m0 + rloc) * 8192 + sg_col;
  const char* b_base = (const char*)B + (size_t)(n0 + rloc) * 8192 + sg_col;
  int ldst = wv * 1024;       // wave-uniform LDS dest offset within granule

  // read-side swizzled offsets
  int offk0 = ((l >> 4) << 4) ^ ((l & 7) << 4);
  int offk1 = offk0 ^ 64;
  int aro = (wm * 128 + (l & 15)) * 128;
  int bro = (wn * 64  + (l & 15)) * 128;

  f32x4 acc[8][4] = {};
  bf16x8 a47A[4][2], b01A[2][2], a47B[4][2], b01B[2][2];

  // prologue: D0 complete (8 loads), then steady-state in-flight set
  // {A(1)G1,G3, B(1)G0-3} (6 loads). vmcnt(6) -> D0 landed. Then issue
  // tile0's ph0 fragments (a47A,b01A) from D0; ph0's LGKM0 gates them.
#pragma unroll
  for (int g = 0; g < 4; ++g) stageA(a_base, lds, ldst, 0, 0, g);
#pragma unroll
  for (int g = 0; g < 4; ++g) stageB(b_base, lds, ldst, 0, 0, g);
  stageA(a_base, lds, ldst, 1, 1, 1);
  stageA(a_base, lds, ldst, 1, 1, 3);
#pragma unroll
  for (int g = 0; g < 4; ++g) stageB(b_base, lds, ldst, 1, 1, g);
  asm volatile("s_waitcnt vmcnt(6)" ::: "memory");
  BAR;
  {
    const char* LA0 = lds + aro;
    const char* LB0 = lds + 65536 + bro;
#pragma unroll
    for (int mf = 0; mf < 4; ++mf) {
      a47A[mf][0] = *(const bf16x8*)(LA0 + (4 + mf) * 2048 + offk0);
      a47A[mf][1] = *(const bf16x8*)(LA0 + (4 + mf) * 2048 + offk1);
    }
#pragma unroll
    for (int nf = 0; nf < 2; ++nf) {
      b01A[nf][0] = *(const bf16x8*)(LB0 + nf * 2048 + offk0);
      b01A[nf][1] = *(const bf16x8*)(LB0 + nf * 2048 + offk1);
    }
  }

#pragma unroll 1
  for (int tt = 0; tt < NKT; tt += 2) {
    kblock<0>(lds, a_base, b_base, ldst, aro, bro, offk0, offk1,
              tt + 1, tt + 2, acc, a47A, b01A, a47B, b01B);
    kblock<1>(lds, a_base, b_base, ldst, aro, bro, offk0, offk1,
              tt + 2, tt + 3, acc, a47B, b01B, a47A, b01A);
  }
  asm volatile("s_waitcnt vmcnt(0) lgkmcnt(0)" ::: "memory");  // drain tails

  // C-write: frag layout col = lane&15, row = (lane>>4)*4 + reg (m89)
  int crow = m0 + wm * 128 + ((l >> 4) << 2);
  int ccol = n0 + wn * 64 + (l & 15);
#pragma unroll
  for (int mf = 0; mf < 8; ++mf)
#pragma unroll
    for (int nf = 0; nf < 4; ++nf)
#pragma unroll
      for (int i = 0; i < 4; ++i)
        C[(size_t)(crow + mf * 16 + i) * N6H + (ccol + nf * 16)] =
            f2bf(acc[mf][nf][i]);
}

// --- round-1 GRU: h_old = features (f32); writes h1 as bf16 only.
__global__ void __launch_bounds__(256)
gru1(const unsigned short* __restrict__ C, const float* __restrict__ h_old,
     const float* __restrict__ b_ih, const float* __restrict__ b_hh,
     unsigned short* __restrict__ h_bf)
{
  int idx = blockIdx.x * 256 + threadIdx.x;
  int b = idx >> 10;
  int j = (idx & 1023) << 2;
  const unsigned short* Cr = C + (size_t)b * N6H;
  u16x4 gir = *(const u16x4*)(Cr + j);
  u16x4 giz = *(const u16x4*)(Cr + HH + j);
  u16x4 gin = *(const u16x4*)(Cr + 2 * HH + j);
  u16x4 ghr = *(const u16x4*)(Cr + 3 * HH + j);
  u16x4 ghz = *(const u16x4*)(Cr + 4 * HH + j);
  u16x4 ghn = *(const u16x4*)(Cr + 5 * HH + j);
  f32x4 bir = *(const f32x4*)(b_ih + j);
  f32x4 biz = *(const f32x4*)(b_ih + HH + j);
  f32x4 bin = *(const f32x4*)(b_ih + 2 * HH + j);
  f32x4 bhr = *(const f32x4*)(b_hh + j);
  f32x4 bhz = *(const f32x4*)(b_hh + HH + j);
  f32x4 bhn = *(const f32x4*)(b_hh + 2 * HH + j);
  f32x4 ho  = *(const f32x4*)(h_old + (size_t)b * HH + j);
  u16x4 hb;
#pragma unroll
  for (int e = 0; e < 4; ++e) {
    float r = 1.f / (1.f + expf(-(bf2f(gir[e]) + bir[e] + bf2f(ghr[e]) + bhr[e])));
    float z = 1.f / (1.f + expf(-(bf2f(giz[e]) + biz[e] + bf2f(ghz[e]) + bhz[e])));
    float n = tanhf(bf2f(gin[e]) + bin[e] + r * (bf2f(ghn[e]) + bhn[e]));
    hb[e] = f2bf((1.f - z) * n + z * ho[e]);
  }
  *(u16x4*)(h_bf + (size_t)b * HH + j) = hb;
}

// --- round-2 GRU fused with FC head: h_old = h1 (bf16); per-block partial
// dot(h2, fc_w) -> atomicAdd(out[b]). out zeroed by memset each call.
__global__ void __launch_bounds__(256)
gru2_fc(const unsigned short* __restrict__ C,
        const unsigned short* __restrict__ h_old_bf,
        const float* __restrict__ b_ih, const float* __restrict__ b_hh,
        const float* __restrict__ fcw, const float* __restrict__ fcb,
        float* __restrict__ out)
{
  int idx = blockIdx.x * 256 + threadIdx.x;
  int b = idx >> 10;
  int j = (idx & 1023) << 2;
  const unsigned short* Cr = C + (size_t)b * N6H;
  u16x4 gir = *(const u16x4*)(Cr + j);
  u16x4 giz = *(const u16x4*)(Cr + HH + j);
  u16x4 gin = *(const u16x4*)(Cr + 2 * HH + j);
  u16x4 ghr = *(const u16x4*)(Cr + 3 * HH + j);
  u16x4 ghz = *(const u16x4*)(Cr + 4 * HH + j);
  u16x4 ghn = *(const u16x4*)(Cr + 5 * HH + j);
  f32x4 bir = *(const f32x4*)(b_ih + j);
  f32x4 biz = *(const f32x4*)(b_ih + HH + j);
  f32x4 bin = *(const f32x4*)(b_ih + 2 * HH + j);
  f32x4 bhr = *(const f32x4*)(b_hh + j);
  f32x4 bhz = *(const f32x4*)(b_hh + HH + j);
  f32x4 bhn = *(const f32x4*)(b_hh + 2 * HH + j);
  u16x4 hob = *(const u16x4*)(h_old_bf + (size_t)b * HH + j);
  f32x4 fw  = *(const f32x4*)(fcw + j);
  float s = 0.f;
#pragma unroll
  for (int e = 0; e < 4; ++e) {
    float r = 1.f / (1.f + expf(-(bf2f(gir[e]) + bir[e] + bf2f(ghr[e]) + bhr[e])));
    float z = 1.f / (1.f + expf(-(bf2f(giz[e]) + biz[e] + bf2f(ghz[e]) + bhz[e])));
    float n = tanhf(bf2f(gin[e]) + bin[e] + r * (bf2f(ghn[e]) + bhn[e]));
    float h = (1.f - z) * n + z * bf2f(hob[e]);
    s += h * fw[e];
  }
#pragma unroll
  for (int off = 32; off > 0; off >>= 1) s += __shfl_down(s, off);
  __shared__ float red[4];
  if ((threadIdx.x & 63) == 0) red[threadIdx.x >> 6] = s;
  __syncthreads();
  if (threadIdx.x == 0) {
    float v = red[0] + red[1] + red[2] + red[3];
    if ((blockIdx.x & 3) == 0) v += fcb[0];
    atomicAdd(&out[b], v);
  }
}

extern "C" void kernel_launch(void* const* d_in, const int* in_sizes, int n_in,
                              void* d_out, int out_size, void* d_ws, size_t ws_size,
                              hipStream_t stream)
{
  const float* feat = (const float*)d_in[0];
  const float* Wih  = (const float*)d_in[1];
  const float* bih  = (const float*)d_in[2];
  const float* Whh  = (const float*)d_in[3];
  const float* bhh  = (const float*)d_in[4];
  const float* fcw  = (const float*)d_in[5];
  const float* fcb  = (const float*)d_in[6];
  float* out = (float*)d_out;

  char* ws = (char*)d_ws;
  unsigned short* Wc   = (unsigned short*)ws;                    // 201326592 B
  unsigned short* Cbuf = (unsigned short*)(ws + 201326592);      // 201326592 B
  unsigned short* hb   = (unsigned short*)(ws + 402653184);      //  33554432 B
  // total: 436207616 B

  hipMemsetAsync(out, 0, (size_t)out_size * sizeof(float), stream);
  prep<<<NB_W + NB_C, 256, 0, stream>>>(Wih, Whh, feat, Wc, hb);

  gemm_bt<<<GRID_GEMM, 512, 0, stream>>>(hb, Wc, Cbuf);
  gru1<<<16384, 256, 0, stream>>>(Cbuf, feat, bih, bhh, hb);

  gemm_bt<<<GRID_GEMM, 512, 0, stream>>>(hb, Wc, Cbuf);
  gru2_fc<<<16384, 256, 0, stream>>>(Cbuf, hb, bih, bhh, fcw, fcb, out);
}